// Round 5
// baseline (124.844 us; speedup 1.0000x reference)
//
#include <hip/hip_runtime.h>
#include <math.h>

#define Bn 16
#define Ln 1444      // 38*38
#define NCn 21
#define Cn 64
#define NBn 23       // ceil(1444/64)
#define KC 1344      // 21*64

// LDS float layout (overlaid):
//   [0,4160)    tile[64][65]      phase 1 only
//   [0,5376)    WS[4][1344]       written after tile dead; live to end
//   [5376,6720) PS[1344]
//   [6720,8064) TU[1344]          Tt, then overlaid by Ul
//   [8064,8505) Rl[441]
//   [8505,8967) Rd[21*22]
//   [8967,8988) Rdg[21]
#define SH_FLOATS 8988

__global__ __launch_bounds__(256, 2) void kOne(const float* __restrict__ cls_pred,
                                               const float* __restrict__ source,
                                               const float* __restrict__ R,
                                               float* __restrict__ fused,
                                               float* __restrict__ src_out,
                                               float* __restrict__ bs,
                                               unsigned int* __restrict__ cnt) {
    int b = blockIdx.x / NBn, m = blockIdx.x % NBn;
    int base = m * 64;
    int lane = threadIdx.x & 63, grp = threadIdx.x >> 6;

    __shared__ float sh[SH_FLOATS];
    __shared__ int cls[64];
    float (*tile)[65] = (float(*)[65])sh;     // [64][65]
    float* WS  = sh;                          // [4][1344]
    float* PS  = sh + 5376;
    float* TU  = sh + 6720;
    float* Rl  = sh + 8064;
    float* Rd  = sh + 8505;                   // [21][22] flat
    float* Rdg = sh + 8967;

    // ---- phase 1a: source tile (coalesced) + R tables ----
#pragma unroll
    for (int cc = 0; cc < 16; cc++) {
        int c = grp * 16 + cc;
        float v = 0.f;
        if (base + lane < Ln) v = source[((size_t)b * Cn + c) * Ln + base + lane];
        tile[c][lane] = v;
    }
    for (int i = threadIdx.x; i < 441; i += 256) {
        float r = R[i];
        Rl[i] = r;
        int aa = i / 21, kk = i % 21;
        Rd[aa * 22 + kk] = r - R[kk * 21 + aa];
    }
    if (threadIdx.x < 21) Rdg[threadIdx.x] = R[threadIdx.x * 22];

    // ---- phase 1b: classify (math identical to passing R3 version) ----
    {
        int p = threadIdx.x >> 2, a = threadIdx.x & 3;
        bool valid = (base + p < Ln);
        const float* q = cls_pred + ((size_t)b * Ln + base + p) * 84 + a * 21;
        float x[21];
#pragma unroll
        for (int i = 0; i < 21; i++) x[i] = valid ? q[i] : 0.f;
        float mx = x[0];
#pragma unroll
        for (int i = 1; i < 21; i++) mx = fmaxf(mx, x[i]);
        float s = 0.f;
#pragma unroll
        for (int i = 0; i < 21; i++) { x[i] = expf(x[i] - mx); s += x[i]; }
        float best = -1.f; int bi = 0;
#pragma unroll
        for (int i = 0; i < 21; i++) {
            float sm = x[i] / s;                     // mimic softmax exp/sum
            if (sm > best) { best = sm; bi = a * 21 + i; }
        }
#pragma unroll
        for (int d = 1; d <= 2; d <<= 1) {
            float ob = __shfl_xor(best, d);
            int oi = __shfl_xor(bi, d);
            if (ob > best || (ob == best && oi < bi)) { best = ob; bi = oi; }
        }
        if (a == 0) cls[p] = valid ? (bi % 21) : 255;
    }
    __syncthreads();   // S1: tile + cls ready

    // ---- phase 1c: merged src write + per-class register sums + sT grab ----
    float sT[16];
    float cs[21];
#pragma unroll
    for (int k = 0; k < 21; k++) cs[k] = 0.f;
#pragma unroll
    for (int jj = 0; jj < 16; jj++) {
        int j = grp * 16 + jj;
        float v = tile[lane][j];                 // stride-65: conflict-free
        sT[jj] = v;
        if (base + j < Ln) src_out[((size_t)b * Ln + base + j) * Cn + lane] = v;
        int k = cls[j];                          // wave-uniform broadcast
#pragma unroll
        for (int kk = 0; kk < 21; kk++) cs[kk] += (kk == k) ? v : 0.f;
    }
    __syncthreads();   // S2: all tile reads done -> tile dead

    // ---- phase 1d: publish per-wave sums (overlays tile), reduce -> bs ----
#pragma unroll
    for (int kk = 0; kk < 21; kk++) WS[grp * KC + kk * 64 + lane] = cs[kk];
    __syncthreads();   // S3: WS ready
    for (int i = threadIdx.x; i < KC; i += 256) {
        float v = WS[i] + WS[KC + i] + WS[2 * KC + i] + WS[3 * KC + i];
        bs[((size_t)b * NBn + m) * KC + i] = v;
    }
    __threadfence();   // release this thread's bs stores to device scope
    __syncthreads();   // S4: every thread's stores fenced
    if (threadIdx.x == 0)
        __hip_atomic_fetch_add(&cnt[b], 1u, __ATOMIC_RELEASE, __HIP_MEMORY_SCOPE_AGENT);

    // ---- per-batch barrier: wait for the batch's 23 producer tiles ----
    if (threadIdx.x == 0) {
        long iters = 0;
        while (__hip_atomic_load(&cnt[b], __ATOMIC_ACQUIRE, __HIP_MEMORY_SCOPE_AGENT) < NBn) {
            __builtin_amdgcn_s_sleep(1);
            if (++iters > (1L << 28)) break;   // safety bound (never expected)
        }
    }
    __syncthreads();   // S5
    __threadfence();   // acquire: invalidate stale cached bs lines

    // ---- phase 2a: stream batch's bs (float4, 23 independent loads) ----
    for (int g = threadIdx.x; g < KC / 4; g += 256) {
        float rx = 0.f, ry = 0.f, rz = 0.f, rw = 0.f;
        float px = 0.f, py = 0.f, pz = 0.f, pw = 0.f;
#pragma unroll
        for (int mm = 0; mm < NBn; mm++) {
            float4 v = *reinterpret_cast<const float4*>(&bs[((size_t)b * NBn + mm) * KC + g * 4]);
            rx += v.x; ry += v.y; rz += v.z; rw += v.w;
            if (mm < m) { px += v.x; py += v.y; pz += v.z; pw += v.w; }  // uniform branch
        }
        PS[g * 4] = px; PS[g * 4 + 1] = py; PS[g * 4 + 2] = pz; PS[g * 4 + 3] = pw;
        TU[g * 4] = rx; TU[g * 4 + 1] = ry; TU[g * 4 + 2] = rz; TU[g * 4 + 3] = rw;
    }
    __syncthreads();   // S6: PS/Tt ready

    // ---- phase 2b: Ul in registers, then overlay onto TU ----
    float u[6];
#pragma unroll
    for (int it = 0; it < 6; it++) {
        int p = threadIdx.x + it * 256;
        if (p < KC) {
            int aa = p >> 6, c = p & 63;
            float s = 0.f;
#pragma unroll
            for (int k = 0; k < 21; k++) s += Rl[k * 21 + aa] * TU[k * 64 + c];
            u[it] = s;
        }
    }
    __syncthreads();   // S7: all Tt reads done
#pragma unroll
    for (int it = 0; it < 6; it++) {
        int p = threadIdx.x + it * 256;
        if (p < KC) TU[p] = u[it];
    }
    __syncthreads();   // S8: Ul ready

    // ---- phase 2c: register running sums + final combine ----
    float ms[21];
#pragma unroll
    for (int k = 0; k < 21; k++) {
        float x = PS[k * 64 + lane];
        if (grp > 0) x += WS[0 * KC + k * 64 + lane];
        if (grp > 1) x += WS[1 * KC + k * 64 + lane];
        if (grp > 2) x += WS[2 * KC + k * 64 + lane];
        ms[k] = x;
    }
    int nvalid = (Ln - base < 64) ? (Ln - base) : 64;
    for (int t = 0; t < 16; t++) {
        int i = grp * 16 + t;
        if (i >= nvalid) break;
        int ci = cls[i];                          // wave-uniform
        float sv = sT[t];
        float acc = TU[ci * 64 + lane] + (((ci != 0) ? 1.f : 0.f) - Rdg[ci]) * sv;
#pragma unroll
        for (int k = 0; k < 21; k++) acc += Rd[ci * 22 + k] * ms[k];
        fused[((size_t)b * Ln + base + i) * Cn + lane] = acc;
#pragma unroll
        for (int kk = 0; kk < 21; kk++) ms[kk] += (kk == ci) ? sv : 0.f;
    }
}

extern "C" void kernel_launch(void* const* d_in, const int* in_sizes, int n_in,
                              void* d_out, int out_size, void* d_ws, size_t ws_size,
                              hipStream_t stream) {
    const float* cls_pred = (const float*)d_in[0];
    const float* source = (const float*)d_in[1];
    const float* cls_r_prob = (const float*)d_in[2];

    float* fused = (float*)d_out;
    float* src_out = fused + (size_t)Bn * Ln * Cn;

    float* bs = (float*)d_ws;                                  // 16*23*1344*4 = 1978368 B
    unsigned int* cnt = (unsigned int*)((char*)d_ws + (size_t)Bn * NBn * KC * 4);  // 64 B

    hipMemsetAsync(cnt, 0, Bn * sizeof(unsigned int), stream);
    hipLaunchKernelGGL(kOne, dim3(Bn * NBn), dim3(256), 0, stream,
                       cls_pred, source, cls_r_prob, fused, src_out, bs, cnt);
}

// Round 6
// 40.510 us; speedup vs baseline: 3.0818x; 3.0818x over previous
//
#include <hip/hip_runtime.h>
#include <math.h>

#define Bn 16
#define Ln 1444      // 38*38
#define NCn 21
#define Cn 64
#define NBn 23       // ceil(1444/64)
#define KC 1344      // 21*64

// ---- Kernel B: classify (LDS-staged) + transpose + per-block class sums ---
// LDS: [0,4160) tile[64][65]; [4160,9536) clsP (5376 floats) -> overlaid by WS[4][1344]
__global__ __launch_bounds__(256) void kB(const float* __restrict__ cls_pred,
                                          const float* __restrict__ source,
                                          int* __restrict__ cls_idx,
                                          float* __restrict__ src_out,
                                          float* __restrict__ bs) {
    int b = blockIdx.x / NBn, m = blockIdx.x % NBn;
    int base = m * 64;
    int lane = threadIdx.x & 63, grp = threadIdx.x >> 6;
    __shared__ float sh[9536];
    __shared__ int cls[64];
    float (*tile)[65] = (float(*)[65])sh;   // [64][65]
    float* clsP = sh + 4160;                // 5376 floats, dead after classify
    float* WS   = sh + 4160;                // [4][1344] overlays clsP

    // stage source tile (coalesced): tile[c][j] = source[b, c, base+j]
#pragma unroll
    for (int cc = 0; cc < 16; cc++) {
        int c = grp * 16 + cc;
        float v = 0.f;
        if (base + lane < Ln) v = source[((size_t)b * Cn + c) * Ln + base + lane];
        tile[c][lane] = v;
    }
    // stage cls_pred tile (perfectly coalesced float4): 64 pos x 84 floats
    {
        const float4* gp = reinterpret_cast<const float4*>(cls_pred + ((size_t)b * Ln + base) * 84);
        int lim4 = (Ln - base) * 21;            // valid float4 count
#pragma unroll
        for (int it = 0; it < 6; it++) {
            int f4 = threadIdx.x + it * 256;
            if (f4 < 1344) {
                float4 v = (f4 < lim4) ? gp[f4] : make_float4(0.f, 0.f, 0.f, 0.f);
                reinterpret_cast<float4*>(clsP)[f4] = v;
            }
        }
    }
    __syncthreads();   // S1: stages ready

    // classify from LDS: thread = position p (64) x anchor a (4); math identical to R3
    {
        int p = threadIdx.x >> 2, a = threadIdx.x & 3;
        bool valid = (base + p < Ln);
        const float* q = clsP + p * 84 + a * 21;
        float x[21];
#pragma unroll
        for (int i = 0; i < 21; i++) x[i] = q[i];
        float mx = x[0];
#pragma unroll
        for (int i = 1; i < 21; i++) mx = fmaxf(mx, x[i]);
        float s = 0.f;
#pragma unroll
        for (int i = 0; i < 21; i++) { x[i] = expf(x[i] - mx); s += x[i]; }
        float best = -1.f; int bi = 0;
#pragma unroll
        for (int i = 0; i < 21; i++) {
            float sm = x[i] / s;                     // exact per-element division (matches ref)
            if (sm > best) { best = sm; bi = a * 21 + i; }
        }
#pragma unroll
        for (int d = 1; d <= 2; d <<= 1) {
            float ob = __shfl_xor(best, d);
            int oi = __shfl_xor(bi, d);
            if (ob > best || (ob == best && oi < bi)) { best = ob; bi = oi; }
        }
        if (a == 0) {
            if (valid) { int k = bi % 21; cls[p] = k; cls_idx[b * Ln + base + p] = k; }
            else cls[p] = 255;
        }
    }
    __syncthreads();   // S2: cls ready, clsP dead (WS may overlay)

    // src write + per-class register sums of own 16 positions
    float cs[21];
#pragma unroll
    for (int k = 0; k < 21; k++) cs[k] = 0.f;
#pragma unroll
    for (int jj = 0; jj < 16; jj++) {
        int j = grp * 16 + jj;
        float v = tile[lane][j];                 // stride-65: conflict-free
        if (base + j < Ln) src_out[((size_t)b * Ln + base + j) * Cn + lane] = v;
        int k = cls[j];                          // wave-uniform broadcast
#pragma unroll
        for (int kk = 0; kk < 21; kk++) cs[kk] += (kk == k) ? v : 0.f;
    }
#pragma unroll
    for (int kk = 0; kk < 21; kk++) WS[grp * KC + kk * 64 + lane] = cs[kk];
    __syncthreads();   // S3: WS ready

    for (int i = threadIdx.x; i < KC; i += 256) {
        float v = WS[i] + WS[KC + i] + WS[2 * KC + i] + WS[3 * KC + i];
        bs[((size_t)b * NBn + m) * KC + i] = v;
    }
}

// ---- Kernel C: batched stream + register running sums (R3, unchanged) -----
__global__ __launch_bounds__(256) void kC(const float* __restrict__ src,
                                          const int* __restrict__ cls_idx,
                                          const float* __restrict__ R,
                                          const float* __restrict__ bs,
                                          float* __restrict__ fused) {
    int b = blockIdx.x / NBn, m = blockIdx.x % NBn;
    int base = m * 64;
    int lane = threadIdx.x & 63, grp = threadIdx.x >> 6;
    __shared__ float PS[KC];       // prefix over blocks < m
    __shared__ float Tt[KC];       // batch totals
    __shared__ float Ul[KC];       // [a*64+c] = sum_k R[k][a]*T[k][c]
    __shared__ float WS[4][KC];    // per-wave chunk class sums
    __shared__ float Rd[21][22];   // R[a][k]-R[k][a]
    __shared__ float Rl[441];
    __shared__ float Rdg[21];
    __shared__ int cls[64];

    // 1: own-chunk sT into 16 registers (issued first, consumed late)
    float sT[16];
#pragma unroll
    for (int t = 0; t < 16; t++) {
        int i = grp * 16 + t;
        sT[t] = (base + i < Ln) ? src[((size_t)b * Ln + base + i) * Cn + lane] : 0.f;
    }
    // 2: cls
    if (threadIdx.x < 64) {
        int k = 255;
        if (base + (int)threadIdx.x < Ln) k = cls_idx[b * Ln + base + threadIdx.x];
        cls[threadIdx.x] = k;
    }
    // 3: R tables
    for (int i = threadIdx.x; i < 441; i += 256) {
        float r = R[i];
        Rl[i] = r;
        int aa = i / 21, kk = i % 21;
        Rd[aa][kk] = r - R[kk * 21 + aa];
    }
    if (threadIdx.x < 21) Rdg[threadIdx.x] = R[threadIdx.x * 22];

    // 4: stream bs as float4 groups — 23 independent batched loads
    for (int g = threadIdx.x; g < KC / 4; g += 256) {
        float rx = 0.f, ry = 0.f, rz = 0.f, rw = 0.f;
        float px = 0.f, py = 0.f, pz = 0.f, pw = 0.f;
#pragma unroll
        for (int mm = 0; mm < NBn; mm++) {
            float4 v = *reinterpret_cast<const float4*>(&bs[((size_t)b * NBn + mm) * KC + g * 4]);
            rx += v.x; ry += v.y; rz += v.z; rw += v.w;
            if (mm < m) { px += v.x; py += v.y; pz += v.z; pw += v.w; }  // uniform branch
        }
        PS[g * 4] = px; PS[g * 4 + 1] = py; PS[g * 4 + 2] = pz; PS[g * 4 + 3] = pw;
        Tt[g * 4] = rx; Tt[g * 4 + 1] = ry; Tt[g * 4 + 2] = rz; Tt[g * 4 + 3] = rw;
    }
    __syncthreads();

    // 5: Ul[a*64+c] = sum_k R[k][a] * T[k][c]
    for (int p = threadIdx.x; p < KC; p += 256) {
        int aa = p >> 6, c = p & 63;
        float u = 0.f;
#pragma unroll
        for (int k = 0; k < 21; k++) u += Rl[k * 21 + aa] * Tt[k * 64 + c];
        Ul[p] = u;
    }

    // 6: own-chunk per-class sums in registers -> WS
    float cs[21];
#pragma unroll
    for (int k = 0; k < 21; k++) cs[k] = 0.f;
#pragma unroll
    for (int t = 0; t < 16; t++) {
        int j = grp * 16 + t;
        int k = cls[j];
        float v = sT[t];
#pragma unroll
        for (int kk = 0; kk < 21; kk++) cs[kk] += (kk == k) ? v : 0.f;
    }
#pragma unroll
    for (int kk = 0; kk < 21; kk++) WS[grp][kk * 64 + lane] = cs[kk];
    __syncthreads();

    // 7: register running sums: ms[k] = PS + chunks before mine
    float ms[21];
#pragma unroll
    for (int k = 0; k < 21; k++) {
        float x = PS[k * 64 + lane];
#pragma unroll
        for (int g = 0; g < 3; g++)
            if (g < grp) x += WS[g][k * 64 + lane];
        ms[k] = x;
    }

    // 8: serial over own 16 positions — register-only dependency chain
    int nvalid = (Ln - base < 64) ? (Ln - base) : 64;
    for (int t = 0; t < 16; t++) {
        int i = grp * 16 + t;
        if (i >= nvalid) break;
        int ci = cls[i];                                 // wave-uniform
        float acc = Ul[ci * 64 + lane] + (((ci != 0) ? 1.f : 0.f) - Rdg[ci]) * sT[t];
#pragma unroll
        for (int k = 0; k < 21; k++) acc += Rd[ci][k] * ms[k];   // broadcast read + reg FMA
        fused[((size_t)b * Ln + base + i) * Cn + lane] = acc;
        float v = sT[t];
#pragma unroll
        for (int kk = 0; kk < 21; kk++) ms[kk] += (kk == ci) ? v : 0.f;
    }
}

extern "C" void kernel_launch(void* const* d_in, const int* in_sizes, int n_in,
                              void* d_out, int out_size, void* d_ws, size_t ws_size,
                              hipStream_t stream) {
    const float* cls_pred = (const float*)d_in[0];
    const float* source = (const float*)d_in[1];
    const float* cls_r_prob = (const float*)d_in[2];

    float* fused = (float*)d_out;
    float* src_out = fused + (size_t)Bn * Ln * Cn;

    char* w = (char*)d_ws;
    int* cls_idx = (int*)w;                                    // 92416 B
    size_t off = ((size_t)Bn * Ln * 4 + 1023) & ~(size_t)1023;
    float* bs = (float*)(w + off);                             // 16*23*1344*4 B

    hipLaunchKernelGGL(kB, dim3(Bn * NBn), dim3(256), 0, stream,
                       cls_pred, source, cls_idx, src_out, bs);
    hipLaunchKernelGGL(kC, dim3(Bn * NBn), dim3(256), 0, stream,
                       src_out, cls_idx, cls_r_prob, bs, fused);
}